// Round 1
// baseline (259.203 us; speedup 1.0000x reference)
//
#include <hip/hip_runtime.h>

// SparseMaxPool: out2d[b,c,i,j] = max(x[b,c,i..j]) on valid diagonals, else 0.
// valid(d=j-i, i): d in [0,14]  (any i)
//                  d in {16,18,..,30} and i%2==0
//                  d in {34,38,..,62} (d%4==2) and i%4==0
// mask[i][j] = valid(j-i, i)  (eye covered by d=0)

struct MaskTable { unsigned long long m[64]; };

constexpr MaskTable make_masks() {
    MaskTable t{};
    for (int i = 0; i < 64; ++i) {
        unsigned long long mm = 0ull;
        for (int j = i; j < 64; ++j) {
            const int d = j - i;
            const bool v = (d <= 14)
                || ((i % 2 == 0) && d >= 16 && d <= 30 && (d % 2 == 0))
                || ((i % 4 == 0) && d >= 34 && d <= 62 && (d % 4 == 2));
            if (v) mm |= (1ull << j);
        }
        t.m[i] = mm;
    }
    return t;
}

__device__ constexpr MaskTable MT = make_masks();

__global__ __launch_bounds__(256) void spmax_kernel(
    const float* __restrict__ x, float* __restrict__ out,
    float* __restrict__ mask_out, int nrow_blocks)
{
    __shared__ float4 xs4[4][16];   // one 64-float row per wave

    const int w    = threadIdx.x >> 6;   // wave id in block
    const int lane = threadIdx.x & 63;

    if ((int)blockIdx.x >= nrow_blocks) {
        // last block: write the 64x64 mask as 0.0/1.0 floats
        #pragma unroll
        for (int k = 0; k < 16; ++k) {
            const int idx = (int)threadIdx.x + 256 * k;
            const int i = idx >> 6, j = idx & 63;
            const int d = j - i;
            const bool v = (d >= 0) && ((d <= 14)
                || (((i & 1) == 0) && d >= 16 && d <= 30 && ((d & 1) == 0))
                || (((i & 3) == 0) && d >= 34 && d <= 62 && ((d & 3) == 2)));
            mask_out[idx] = v ? 1.0f : 0.0f;
        }
        return;
    }

    const int row = (int)blockIdx.x * 4 + w;      // (b*C + c)
    float* xsf = reinterpret_cast<float*>(&xs4[w][0]);
    xsf[lane] = x[(size_t)row * 64 + lane];       // coalesced 1KB/block
    __syncthreads();

    float* orow = out + (size_t)row * 4096;

    // lane j scans i = 63..0 maintaining r = max(x[i..j]).
    // At pass i==lane, r is re-initialized to x[i] (kills junk from i>j passes).
    float r = 0.0f;
    #pragma unroll
    for (int g = 15; g >= 0; --g) {
        const float4 X = xs4[w][g];               // uniform ds_read_b128 broadcast
        const float xi[4] = {X.x, X.y, X.z, X.w};
        #pragma unroll
        for (int s = 3; s >= 0; --s) {
            const int i = 4 * g + s;
            const float v = xi[s];
            const float t = fmaxf(r, v);
            r = (lane == i) ? v : t;
            const float val = ((MT.m[i] >> lane) & 1ull) ? r : 0.0f;
            orow[i * 64 + lane] = val;            // coalesced 256B row store
        }
    }
}

extern "C" void kernel_launch(void* const* d_in, const int* in_sizes, int n_in,
                              void* d_out, int out_size, void* d_ws, size_t ws_size,
                              hipStream_t stream) {
    const float* x = (const float*)d_in[0];
    float* out = (float*)d_out;
    const int rows = in_sizes[0] / 64;            // 32*512 = 16384
    const int nrow_blocks = rows / 4;             // 4096 (rows % 4 == 0)
    float* mask_out = out + (out_size - 64 * 64); // mask trails x2d
    spmax_kernel<<<nrow_blocks + 1, 256, 0, stream>>>(x, out, mask_out, nrow_blocks);
}

// Round 2
// 253.565 us; speedup vs baseline: 1.0222x; 1.0222x over previous
//
#include <hip/hip_runtime.h>
#include <math.h>

// SparseMaxPool: out2d[b,c,i,j] = max(x[b,c,i..j]) on valid diagonals, else 0.
// valid(d=j-i, i): d in [0,14]  (any i)
//                  d in {16,18,..,30} and i%2==0
//                  d in {34,38,..,62} (d%4==2) and i%4==0
// mask[i][j] = valid(j-i, i)

__device__ __forceinline__ bool valid_ij(int i, int j) {
    const int d = j - i;
    return ((unsigned)d <= 14u)
        || (((i & 1) == 0) && (unsigned)(d - 16) <= 14u && ((d & 1) == 0))
        || (((i & 3) == 0) && (unsigned)(d - 34) <= 28u && ((d & 3) == 2));
}

// Each block: 16 rows. Each wave: 4 rows; 16 lanes per row; each lane owns
// 4 consecutive j (float4 stores). Running max r[s]=max(x[i..4*jq+s]) scanned
// i=63..0; invalid entries zeroed by multiplying with a 0/1 mask float staged
// in LDS.
__global__ __launch_bounds__(256) void spmax_kernel(
    const float* __restrict__ x, float* __restrict__ out,
    float* __restrict__ mask_out, int nblocks)
{
    __shared__ __align__(16) float xs[16 * 68];   // 16 rows, +4 pad (bank spread)
    __shared__ __align__(16) float mf[64 * 64];   // 0/1 mask floats, 16 KB

    const int tid = threadIdx.x;

    if ((int)blockIdx.x >= nblocks) {
        // last block: write the 64x64 mask as 0.0/1.0 floats
        #pragma unroll
        for (int k = 0; k < 16; ++k) {
            const int idx = tid + 256 * k;
            mask_out[idx] = valid_ij(idx >> 6, idx & 63) ? 1.0f : 0.0f;
        }
        return;
    }

    // stage 16 rows of x: one float4 per thread, coalesced 4 KB
    {
        const float4 v = reinterpret_cast<const float4*>(x)[(size_t)blockIdx.x * 256 + tid];
        const int r = tid >> 4, c4 = tid & 15;
        *reinterpret_cast<float4*>(&xs[r * 68 + 4 * c4]) = v;
    }
    // stage mask floats: 16 entries per thread
    #pragma unroll
    for (int k = 0; k < 16; ++k) {
        const int idx = tid + 256 * k;
        mf[idx] = valid_ij(idx >> 6, idx & 63) ? 1.0f : 0.0f;
    }
    __syncthreads();

    const int lane = tid & 63;
    const int w    = tid >> 6;
    const int rg   = lane >> 4;        // row within wave's group of 4
    const int jq   = lane & 15;        // j quad: owns j = 4*jq .. 4*jq+3
    const int lrow = w * 4 + rg;       // 0..15
    const size_t grow = (size_t)blockIdx.x * 16 + lrow;
    float* obase = out + grow * 4096 + 4 * jq;
    const float* xrow = &xs[lrow * 68];
    const float* mrow = &mf[4 * jq];

    float r0 = -INFINITY, r1 = -INFINITY, r2 = -INFINITY, r3 = -INFINITY;

    #pragma unroll
    for (int g = 15; g >= 0; --g) {
        const float4 X = *reinterpret_cast<const float4*>(&xrow[4 * g]);  // conflict-free
        const float xi4[4] = {X.x, X.y, X.z, X.w};
        #pragma unroll
        for (int s3 = 3; s3 >= 0; --s3) {
            const int i = 4 * g + s3;
            const float v = xi4[s3];
            r0 = fmaxf(r0, v); r1 = fmaxf(r1, v);
            r2 = fmaxf(r2, v); r3 = fmaxf(r3, v);
            // re-init the lane/slot where j == i (kills the i>j garbage phase)
            const bool hit = (jq == (i >> 2));
            switch (i & 3) {                       // compile-time per unrolled i
                case 0: r0 = hit ? v : r0; break;
                case 1: r1 = hit ? v : r1; break;
                case 2: r2 = hit ? v : r2; break;
                case 3: r3 = hit ? v : r3; break;
            }
            const float4 m = *reinterpret_cast<const float4*>(&mrow[i * 64]); // 2-way bcast, free
            float4 o;
            o.x = r0 * m.x; o.y = r1 * m.y; o.z = r2 * m.z; o.w = r3 * m.w;
            *reinterpret_cast<float4*>(obase + i * 64) = o;  // 4x256B coalesced
        }
    }
}

extern "C" void kernel_launch(void* const* d_in, const int* in_sizes, int n_in,
                              void* d_out, int out_size, void* d_ws, size_t ws_size,
                              hipStream_t stream) {
    const float* x = (const float*)d_in[0];
    float* out = (float*)d_out;
    const int rows = in_sizes[0] / 64;            // 32*512 = 16384
    const int nblocks = rows / 16;                // 1024
    float* mask_out = out + (out_size - 64 * 64); // mask trails x2d
    spmax_kernel<<<nblocks + 1, 256, 0, stream>>>(x, out, mask_out, nblocks);
}